// Round 1
// baseline (153.272 us; speedup 1.0000x reference)
//
#include <hip/hip_runtime.h>
#include <math.h>

// Sizes (fixed by the reference problem)
#define BSZ 64
#define DV  1024
#define NQ  32
#define NS  1024
#define DD  128

#define ALPHA 0.5f

typedef __attribute__((ext_vector_type(8))) int   int8v;    // 32B fp8 MFMA A/B frag (8 VGPR)
typedef __attribute__((ext_vector_type(4))) float floatx4;  // MFMA C/D frag
#define SCALE1 127      // e8m0 byte 0x7F = 2^0 = 1.0

// ==================== fused kernel ====================
// blocks 0..511  : multi-vector max-sim scores. Block = (bg of 8 b's, c).
//   Phase A: convert q_multi rows for this bg to fp8 chunks in LDS (once per block).
//   Phase B: stream d_multi[c] fp32 from L2 (XCD-swizzled -> resident), convert to
//            fp8 in registers (bit-identical bytes to the old db8 prep), and run
//            16 mfma_scale (8 b x 2 nt) per st-tile with running per-lane fmax.
//   d L2 traffic: 512 blocks x 512KB = 256MB ~ 7.4us == MFMA time (balanced).
// blocks 512..575: single-vector CE loss rows (exact fp32, unchanged math).
__launch_bounds__(256, 2)
__global__ void fused_kernel(const float* __restrict__ qm, const float* __restrict__ dm,
                             const float* __restrict__ qs, const float* __restrict__ ds,
                             float* __restrict__ scores, float* __restrict__ svrow) {
    __shared__ __align__(32) unsigned char lds_q[16 * 2048];  // 32 KB fp8 A-chunks
    __shared__ float lds_smax[4][8][32];                      // 4 KB (separate: waves race lds_q)
    __shared__ float row[BSZ];

    int bid = blockIdx.x;
    int t = threadIdx.x;

    if (bid >= 512) {
        // ---- single-vector CE loss rows (verbatim from verified prep) ----
        int b = bid - 512;
        int c = t >> 2, part = t & 3;
        const float4* qv = (const float4*)(qs + b * DV);
        const float4* dv = (const float4*)(ds + c * DV);
        float acc = 0.f;
        int k0 = part * 64;
#pragma unroll 8
        for (int k = k0; k < k0 + 64; ++k) {
            float4 a = qv[k], bb = dv[k];
            acc += a.x * bb.x + a.y * bb.y + a.z * bb.z + a.w * bb.w;
        }
        acc += __shfl_xor(acc, 1);
        acc += __shfl_xor(acc, 2);
        if (part == 0) row[c] = acc;
        __syncthreads();
        if (t < BSZ) {
            float v = row[t];
            float m = v;
#pragma unroll
            for (int o = 1; o < 64; o <<= 1) m = fmaxf(m, __shfl_xor(m, o));
            float e = expf(v - m);
#pragma unroll
            for (int o = 1; o < 64; o <<= 1) e += __shfl_xor(e, o);
            float lse = m + logf(e);
            if (t == 0) svrow[b] = lse - row[b];
        }
        return;
    }

    // ---- multi-vector path ----
    int x = bid & 7, rr = bid >> 3;
    int c  = x * 8 + (rr & 7);     // XCD x keeps c in [8x,8x+8): 4MB fp32 d-slice L2-resident
    int bg = rr >> 3;              // 0..7 -> query rows b = bg*8 .. bg*8+7
    int w = t >> 6, l = t & 63;
    int lane16 = l & 15, quad = (l >> 4) & 3;

    // Phase A: q fp32 -> fp8 chunks in LDS. Wave w converts chunks 4w..4w+3.
    // Chunk ch = bi*2+nt: lane l holds q[bg*8+bi][nt*16+(l&15)][quad*32 .. +32] (32B).
#pragma unroll
    for (int k = 0; k < 4; ++k) {
        int ch = w * 4 + k;
        int bi = ch >> 1, nt = ch & 1;
        const float* src = qm + ((size_t)((bg * 8 + bi) * NQ + nt * 16 + lane16)) * DD + quad * 32;
        int dw[8];
#pragma unroll
        for (int j = 0; j < 8; ++j) {
            float4 v = ((const float4*)src)[j];
            int d0 = __builtin_amdgcn_cvt_pk_fp8_f32(v.x, v.y, 0, false);
            dw[j]  = __builtin_amdgcn_cvt_pk_fp8_f32(v.z, v.w, d0, true);
        }
        int4* dst = (int4*)(lds_q + ch * 2048 + l * 32);
        dst[0] = make_int4(dw[0], dw[1], dw[2], dw[3]);
        dst[1] = make_int4(dw[4], dw[5], dw[6], dw[7]);
    }
    __syncthreads();

    // Every wave pulls all 16 A-frags into registers (one-time ~32KB LDS read).
    int8v af[8][2];
#pragma unroll
    for (int bi = 0; bi < 8; ++bi)
#pragma unroll
        for (int nt = 0; nt < 2; ++nt)
            af[bi][nt] = *(const int8v*)(lds_q + (bi * 2 + nt) * 2048 + l * 32);

    float mx[8][2][4];
#pragma unroll
    for (int bi = 0; bi < 8; ++bi)
#pragma unroll
        for (int nt = 0; nt < 2; ++nt)
#pragma unroll
            for (int r = 0; r < 4; ++r) mx[bi][nt][r] = -1e30f;

    // Phase B: wave w owns st = w + 4i (same st->wave map as verified kernel,
    // so fmax order and fp8 bytes are bit-identical). 1-tile register prefetch.
    const float* dcur = dm + ((size_t)(c * NS + w * 16 + lane16)) * DD + quad * 32;
    float4 raw[8];
#pragma unroll
    for (int j = 0; j < 8; ++j) raw[j] = ((const float4*)dcur)[j];
    const float* dnext = dcur + 4 * 16 * DD;    // advance 4 st-tiles (8192 floats)

#pragma unroll 1
    for (int i = 0; i < 16; ++i) {
        // convert current tile (loads issued last iter -> already landed)
        int8v bf;
#pragma unroll
        for (int j = 0; j < 8; ++j) {
            int d0 = __builtin_amdgcn_cvt_pk_fp8_f32(raw[j].x, raw[j].y, 0, false);
            bf[j]  = __builtin_amdgcn_cvt_pk_fp8_f32(raw[j].z, raw[j].w, d0, true);
        }
        // prefetch next tile under the MFMA phase (~550 cyc covers L2 latency)
        if (i < 15) {
#pragma unroll
            for (int j = 0; j < 8; ++j) raw[j] = ((const float4*)dnext)[j];
            dnext += 4 * 16 * DD;
        }
#pragma unroll
        for (int bi = 0; bi < 8; ++bi)
#pragma unroll
            for (int nt = 0; nt < 2; ++nt) {
                floatx4 acc = __builtin_amdgcn_mfma_scale_f32_16x16x128_f8f6f4(
                    af[bi][nt], bf, (floatx4){0.f, 0.f, 0.f, 0.f},
                    0, 0,                 // cbsz=fp8(e4m3), blgp=fp8(e4m3)
                    0, SCALE1,            // scale_a = 1.0
                    0, SCALE1);           // scale_b = 1.0
                // C/D: col(s)=lane&15, row(n)=quad*4+r -> independent running fmax
#pragma unroll
                for (int r = 0; r < 4; ++r)
                    mx[bi][nt][r] = fmaxf(mx[bi][nt][r], acc[r]);
            }
    }

    // ---- end-of-kernel reduction (verified scheme, widened to 8 b's) ----
#pragma unroll
    for (int bi = 0; bi < 8; ++bi)
#pragma unroll
        for (int nt = 0; nt < 2; ++nt)
#pragma unroll
            for (int r = 0; r < 4; ++r) {
                float v = mx[bi][nt][r];
                v = fmaxf(v, __shfl_xor(v, 1));
                v = fmaxf(v, __shfl_xor(v, 2));
                v = fmaxf(v, __shfl_xor(v, 4));
                v = fmaxf(v, __shfl_xor(v, 8));
                mx[bi][nt][r] = v;
            }
    if (lane16 == 0) {
#pragma unroll
        for (int bi = 0; bi < 8; ++bi)
#pragma unroll
            for (int nt = 0; nt < 2; ++nt)
#pragma unroll
                for (int r = 0; r < 4; ++r)
                    lds_smax[w][bi][nt * 16 + quad * 4 + r] = mx[bi][nt][r];
    }
    __syncthreads();
    {
        int bi = t >> 5, n = t & 31;   // 256 threads = 8 b's x 32 q-rows
        float v = fmaxf(fmaxf(lds_smax[0][bi][n], lds_smax[1][bi][n]),
                        fmaxf(lds_smax[2][bi][n], lds_smax[3][bi][n]));
#pragma unroll
        for (int o = 1; o < 32; o <<= 1) v += __shfl_xor(v, o);
        if (n == 0) scores[(bg * 8 + bi) * BSZ + c] = v;
    }
}

// ==================== finisher ====================
__global__ void finish_kernel(const float* __restrict__ scores, const float* __restrict__ svrow,
                              float* __restrict__ out) {
    int t = threadIdx.x;  // 64
    float pos = scores[t * BSZ + t];
    float neg = -1e30f;
    for (int cc = 0; cc < BSZ; ++cc)
        if (cc != t) neg = fmaxf(neg, scores[t * BSZ + cc]);
    float xx = neg - pos;
    float sp = fmaxf(xx, 0.f) + log1pf(expf(-fabsf(xx)));   // stable softplus
    float sv = svrow[t];
#pragma unroll
    for (int o = 1; o < 64; o <<= 1) {
        sp += __shfl_xor(sp, o);
        sv += __shfl_xor(sv, o);
    }
    if (t == 0) out[0] = ALPHA * sv + (1.0f - ALPHA) * (sp * (1.0f / BSZ));
}

// ==================== launch ====================
extern "C" void kernel_launch(void* const* d_in, const int* in_sizes, int n_in,
                              void* d_out, int out_size, void* d_ws, size_t ws_size,
                              hipStream_t stream) {
    const float* q_single = (const float*)d_in[0];
    const float* d_single = (const float*)d_in[1];
    const float* q_multi  = (const float*)d_in[2];
    const float* d_multi  = (const float*)d_in[3];
    float* out = (float*)d_out;

    // ws: scores 16KB | svrow 256B  (db8/qb8 staging buffers eliminated)
    float* scores = (float*)d_ws;
    float* svrow  = (float*)((char*)d_ws + 16384);

    fused_kernel<<<576, 256, 0, stream>>>(q_multi, d_multi, q_single, d_single,
                                          scores, svrow);
    finish_kernel<<<1, 64, 0, stream>>>(scores, svrow, out);
}